// Round 1
// baseline (4467.314 us; speedup 1.0000x reference)
//
#include <hip/hip_runtime.h>
#include <math.h>

// Problem constants (match reference)
#define NEG_SLOPE   0.2f
#define CONSUME_R   0.1f     // RADIUS*2
#define ACCEL_SCALE 0.01f
#define MAX_VEL     0.1f

// ---------------------------------------------------------------------------
// Kernel 1: per-node precompute. hs = x@W, a_src = hs@att_src, a_dst = hs@att_dst
// Packed per node (stride 8 floats, 32B): [hs0..hs4, a_src, a_dst, 0]
// ---------------------------------------------------------------------------
__global__ __launch_bounds__(256) void k_node_pre(
    const float* __restrict__ x, const float* __restrict__ W,
    const float* __restrict__ att_src, const float* __restrict__ att_dst,
    float* __restrict__ npack, int n)
{
    int i = blockIdx.x * 256 + threadIdx.x;
    if (i >= n) return;
    float xr[5];
#pragma unroll
    for (int k = 0; k < 5; ++k) xr[k] = x[(size_t)i * 5 + k];
    float hs[5];
#pragma unroll
    for (int c = 0; c < 5; ++c) {
        float s = 0.f;
#pragma unroll
        for (int k = 0; k < 5; ++k) s += xr[k] * W[k * 5 + c];
        hs[c] = s;
    }
    float a_s = 0.f, a_d = 0.f;
#pragma unroll
    for (int c = 0; c < 5; ++c) { a_s += hs[c] * att_src[c]; a_d += hs[c] * att_dst[c]; }
    float4 p0 = make_float4(hs[0], hs[1], hs[2], hs[3]);
    float4 p1 = make_float4(hs[4], a_s, a_d, 0.f);
    *(float4*)(npack + (size_t)i * 8)     = p0;
    *(float4*)(npack + (size_t)i * 8 + 4) = p1;
}

// ---------------------------------------------------------------------------
// Kernel 2: edge pass. Softmax without max-shift (logits bounded, fp32 safe):
//   ev = exp(leaky_relu(a_src[s] + a_dst[d] + a_e))
//   acc[d] += [ev*hs[s], ev] ; cnt[s] += close | cell<<16
// ---------------------------------------------------------------------------
__global__ __launch_bounds__(256) void k_edge(
    const int* __restrict__ ei, const float* __restrict__ ea,
    const float* __restrict__ We, const float* __restrict__ att_edge,
    const float* __restrict__ npack, float* __restrict__ acc,
    int* __restrict__ cnt, int nE)
{
    int e = blockIdx.x * 256 + threadIdx.x;
    if (e >= nE) return;

    // a_e = edge_attr @ (We @ att_edge); We@att_edge are 2 uniform scalars
    float v0 = 0.f, v1 = 0.f;
#pragma unroll
    for (int c = 0; c < 5; ++c) { v0 += We[c] * att_edge[c]; v1 += We[5 + c] * att_edge[c]; }

    int s = ei[e];
    int d = ei[nE + e];
    float2 at = *(const float2*)(ea + (size_t)e * 2);   // [dist, cell_edge]

    const float4 p0 = *(const float4*)(npack + (size_t)s * 8);       // hs0..3
    const float2 p1 = *(const float2*)(npack + (size_t)s * 8 + 4);   // hs4, a_src
    float a_dst_d = npack[(size_t)d * 8 + 6];

    float z = p1.y + a_dst_d + (at.x * v0 + at.y * v1);
    float l = z > 0.f ? z : NEG_SLOPE * z;
    float ev = __expf(l);

    float* ad = acc + (size_t)d * 8;
    unsafeAtomicAdd(ad + 0, ev * p0.x);
    unsafeAtomicAdd(ad + 1, ev * p0.y);
    unsafeAtomicAdd(ad + 2, ev * p0.z);
    unsafeAtomicAdd(ad + 3, ev * p0.w);
    unsafeAtomicAdd(ad + 4, ev * p1.x);
    unsafeAtomicAdd(ad + 5, ev);

    int cb = (at.x < CONSUME_R ? 1 : 0) | (at.y == 1.0f ? (1 << 16) : 0);
    if (cb) atomicAdd(cnt + s, cb);
}

// ---------------------------------------------------------------------------
// Kernel 3: finalize nodes. GAT out -> MLP -> physics -> new_x rows; block-
// reduce [sum|vx|, sum|vy|, border_cost, consumed, dead] into scal[0..4].
// ---------------------------------------------------------------------------
__global__ __launch_bounds__(256) void k_final(
    const float* __restrict__ x, const float* __restrict__ acc,
    const int* __restrict__ cnt,
    const float* __restrict__ gat_bias, const float* __restrict__ W1,
    const float* __restrict__ b1, const float* __restrict__ W2,
    const float* __restrict__ b2,
    float* __restrict__ out, float* __restrict__ scal, int n)
{
    int i = blockIdx.x * 256 + threadIdx.x;
    float part[5] = {0.f, 0.f, 0.f, 0.f, 0.f};

    if (i < n) {
        const float* a = acc + (size_t)i * 8;
        float inv = 1.0f / fmaxf(a[5], 1e-16f);
        float h[5];
#pragma unroll
        for (int c = 0; c < 5; ++c) h[c] = a[c] * inv + gat_bias[c];
        float t[5];
#pragma unroll
        for (int c = 0; c < 5; ++c) {
            float s = b1[c];
#pragma unroll
            for (int k = 0; k < 5; ++k) s += h[k] * W1[k * 5 + c];
            t[c] = fmaxf(s, 0.f);
        }
        float u0 = b2[0], u1 = b2[1];
#pragma unroll
        for (int k = 0; k < 5; ++k) { u0 += t[k] * W2[k * 2]; u1 += t[k] * W2[k * 2 + 1]; }
        u0 = fmaxf(u0, 0.f) * 2.f - 1.f;
        u1 = fmaxf(u1, 0.f) * 2.f - 1.f;

        float px = x[(size_t)i * 5],     py = x[(size_t)i * 5 + 1];
        float vx = x[(size_t)i * 5 + 2], vy = x[(size_t)i * 5 + 3];
        float ty = x[(size_t)i * 5 + 4];
        float mask = (ty == 1.0f) ? 1.0f : 0.0f;
        float nvx = fminf(fmaxf(vx + u0 * ACCEL_SCALE * mask, -MAX_VEL), MAX_VEL);
        float nvy = fminf(fmaxf(vy + u1 * ACCEL_SCALE * mask, -MAX_VEL), MAX_VEL);
        float npx = px + nvx, npy = py + nvy;

        out[(size_t)i * 5]     = npx;
        out[(size_t)i * 5 + 1] = npy;
        out[(size_t)i * 5 + 2] = nvx;
        out[(size_t)i * 5 + 3] = nvy;
        out[(size_t)i * 5 + 4] = ty;

        part[0] = fabsf(nvx);
        part[1] = fabsf(nvy);
        float bc = 0.f;
        if (fabsf(npx) > 1.0f) bc += logf(fabsf(npx) + 1e-6f);
        if (fabsf(npy) > 1.0f) bc += logf(fabsf(npy) + 1e-6f);
        part[2] = bc;
        int c = cnt[i];
        part[3] = (ty == 0.0f && (c & 0xffff) >= 3) ? 1.f : 0.f;
        part[4] = (ty == 1.0f && (c >> 16) < 1) ? 1.f : 0.f;
    }

    // wave64 shuffle reduce, then cross-wave via LDS
    __shared__ float sm[4][5];
#pragma unroll
    for (int q = 0; q < 5; ++q)
#pragma unroll
        for (int off = 32; off > 0; off >>= 1)
            part[q] += __shfl_down(part[q], off);
    int lane = threadIdx.x & 63, wid = threadIdx.x >> 6;
    if (lane == 0)
#pragma unroll
        for (int q = 0; q < 5; ++q) sm[wid][q] = part[q];
    __syncthreads();
    if (threadIdx.x == 0) {
#pragma unroll
        for (int q = 0; q < 5; ++q) {
            float s = sm[0][q] + sm[1][q] + sm[2][q] + sm[3][q];
            unsafeAtomicAdd(scal + q, s);
        }
    }
}

// ---------------------------------------------------------------------------
// Kernel 4: write the 5 scalar tail outputs
// ---------------------------------------------------------------------------
__global__ void k_tail(const float* __restrict__ scal, float* __restrict__ out, int n)
{
    if (threadIdx.x == 0 && blockIdx.x == 0) {
        size_t base = (size_t)n * 5;
        float invn = 1.0f / (float)n;
        out[base + 0] = scal[0] * invn;   // mean |vx|
        out[base + 1] = scal[1] * invn;   // mean |vy|
        out[base + 2] = scal[2];          // border cost
        out[base + 3] = scal[3];          // consumed (exact integer in fp32)
        out[base + 4] = scal[4];          // dead
    }
}

extern "C" void kernel_launch(void* const* d_in, const int* in_sizes, int n_in,
                              void* d_out, int out_size, void* d_ws, size_t ws_size,
                              hipStream_t stream)
{
    const float* x        = (const float*)d_in[0];
    const int*   ei       = (const int*)  d_in[1];
    const float* ea       = (const float*)d_in[2];
    const float* W        = (const float*)d_in[3];
    const float* att_src  = (const float*)d_in[4];
    const float* att_dst  = (const float*)d_in[5];
    const float* We       = (const float*)d_in[6];
    const float* att_edge = (const float*)d_in[7];
    const float* gat_bias = (const float*)d_in[8];
    const float* W1       = (const float*)d_in[9];
    const float* b1       = (const float*)d_in[10];
    const float* W2       = (const float*)d_in[11];
    const float* b2       = (const float*)d_in[12];

    int n  = in_sizes[0] / 5;
    int nE = in_sizes[1] / 2;

    // Workspace layout (contiguous): npack[n*8] | acc[n*8] | cnt[n] | scal[8]
    float* ws    = (float*)d_ws;
    float* npack = ws;
    float* acc   = ws + (size_t)n * 8;
    int*   cnt   = (int*)(acc + (size_t)n * 8);
    float* scal  = (float*)(cnt + n);

    // zero the accumulated region (acc + cnt + scal) in one memset
    size_t zbytes = ((size_t)n * 8 + (size_t)n + 8) * sizeof(float);
    hipMemsetAsync(acc, 0, zbytes, stream);

    k_node_pre<<<(n + 255) / 256, 256, 0, stream>>>(x, W, att_src, att_dst, npack, n);
    k_edge<<<(nE + 255) / 256, 256, 0, stream>>>(ei, ea, We, att_edge, npack, acc, cnt, nE);
    k_final<<<(n + 255) / 256, 256, 0, stream>>>(x, acc, cnt, gat_bias, W1, b1, W2, b2,
                                                 (float*)d_out, scal, n);
    k_tail<<<1, 64, 0, stream>>>(scal, (float*)d_out, n);
}

// Round 2
// 1797.840 us; speedup vs baseline: 2.4848x; 2.4848x over previous
//
#include <hip/hip_runtime.h>
#include <math.h>

#define NEG_SLOPE   0.2f
#define CONSUME_R   0.1f     // RADIUS*2
#define ACCEL_SCALE 0.01f
#define MAX_VEL     0.1f

#define NBUCK  256
#define TPB    256
#define EPT    32
#define EPB    (TPB*EPT)     // 8192 edges per block
#define MAXNPB 1024

// bucket id + local index for node v; npb = nodes per bucket
__device__ __forceinline__ unsigned bucket_of(unsigned v, unsigned npb, float inv_npb,
                                              unsigned* loc)
{
    unsigned b = (unsigned)((float)v * inv_npb);
    unsigned lo = b * npb;
    if (v < lo)            { --b; lo -= npb; }
    else if (v >= lo + npb){ ++b; lo += npb; }
    *loc = v - lo;
    return b;
}

// ---------------------------------------------------------------------------
// Node precompute: apack[i] = (a_src_i, a_dst_i) fp32; hpack[i] = hs in bf16
// ---------------------------------------------------------------------------
__global__ __launch_bounds__(256) void k_pre(
    const float* __restrict__ x, const float* __restrict__ W,
    const float* __restrict__ att_src, const float* __restrict__ att_dst,
    float2* __restrict__ apack, uint4* __restrict__ hpack, int n)
{
    int i = blockIdx.x * 256 + threadIdx.x;
    if (i >= n) return;
    float xr[5];
#pragma unroll
    for (int k = 0; k < 5; ++k) xr[k] = x[(size_t)i * 5 + k];
    float hs[5];
#pragma unroll
    for (int c = 0; c < 5; ++c) {
        float s = 0.f;
#pragma unroll
        for (int k = 0; k < 5; ++k) s += xr[k] * W[k * 5 + c];
        hs[c] = s;
    }
    float a_s = 0.f, a_d = 0.f;
#pragma unroll
    for (int c = 0; c < 5; ++c) { a_s += hs[c] * att_src[c]; a_d += hs[c] * att_dst[c]; }
    apack[i] = make_float2(a_s, a_d);
    unsigned b[5];
#pragma unroll
    for (int c = 0; c < 5; ++c) {   // round-to-nearest-even bf16
        unsigned u = __float_as_uint(hs[c]);
        b[c] = (u + 0x7FFFu + ((u >> 16) & 1u)) >> 16;
    }
    hpack[i] = make_uint4(b[0] | (b[1] << 16), b[2] | (b[3] << 16), b[4], 0u);
}

// ---------------------------------------------------------------------------
// Per-block bucket histograms (dst domain; src domain predicated).
// histG layout: [col][blk], col 0..255 = dst buckets, 256..511 = src buckets.
// ---------------------------------------------------------------------------
__global__ __launch_bounds__(TPB) void k_hist(
    const int* __restrict__ ei, const float* __restrict__ ea,
    int* __restrict__ histG, int NB, int nE, unsigned npb, float inv_npb)
{
    __shared__ int hd[NBUCK], hsrc[NBUCK];
    int t = threadIdx.x;
    hd[t] = 0; hsrc[t] = 0;
    __syncthreads();
    int base = blockIdx.x * EPB;
#pragma unroll 4
    for (int k = 0; k < EPT; ++k) {
        int e = base + k * TPB + t;
        if (e < nE) {
            unsigned s = (unsigned)ei[e];
            unsigned d = (unsigned)ei[nE + e];
            float2 at = ((const float2*)ea)[e];
            unsigned loc;
            unsigned bd = bucket_of(d, npb, inv_npb, &loc);
            atomicAdd(&hd[bd], 1);
            bool close = at.x < CONSUME_R;
            bool cell  = (at.y == 1.0f);
            if (close || cell) {
                unsigned bs = bucket_of(s, npb, inv_npb, &loc);
                atomicAdd(&hsrc[bs], 1);
            }
        }
    }
    __syncthreads();
    histG[(size_t)t * NB + blockIdx.x]            = hd[t];
    histG[(size_t)(NBUCK + t) * NB + blockIdx.x]  = hsrc[t];
}

// ---------------------------------------------------------------------------
// Exclusive scan per bucket column (in place -> per-block bases, bucket-rel),
// then bucket starts. One block, 512 threads (one column each).
// ---------------------------------------------------------------------------
__global__ __launch_bounds__(512) void k_scan(
    int* __restrict__ histG, int* __restrict__ startD, int* __restrict__ startS, int NB)
{
    __shared__ int tot[512];
    int t = threadIdx.x;
    int* col = histG + (size_t)t * NB;
    int run = 0;
#pragma unroll 4
    for (int i = 0; i < NB; ++i) { int v = col[i]; col[i] = run; run += v; }
    tot[t] = run;
    __syncthreads();
    if (t == 0) {
        int r = 0;
        for (int b = 0; b < NBUCK; ++b) { startD[b] = r; r += tot[b]; }
        startD[NBUCK] = r;
    }
    if (t == 1) {
        int r = 0;
        for (int b = 0; b < NBUCK; ++b) { startS[b] = r; r += tot[NBUCK + b]; }
        startS[NBUCK] = r;
    }
}

// ---------------------------------------------------------------------------
// Scatter: compute ev, place payloads into bucket regions (rank via LDS
// atomic return). payD = {src | dloc<<18, ev}; payS = sloc | close<<10 | cell<<11
// ---------------------------------------------------------------------------
__global__ __launch_bounds__(TPB) void k_scatter(
    const int* __restrict__ ei, const float* __restrict__ ea,
    const float2* __restrict__ apack,
    const float* __restrict__ We, const float* __restrict__ att_edge,
    const int* __restrict__ histG,
    const int* __restrict__ startD, const int* __restrict__ startS,
    int2* __restrict__ payD, unsigned* __restrict__ payS,
    int NB, int nE, unsigned npb, float inv_npb)
{
    __shared__ int baseD[NBUCK], baseS[NBUCK], cD[NBUCK], cS[NBUCK];
    int t = threadIdx.x;
    baseD[t] = startD[t] + histG[(size_t)t * NB + blockIdx.x];
    baseS[t] = startS[t] + histG[(size_t)(NBUCK + t) * NB + blockIdx.x];
    cD[t] = 0; cS[t] = 0;
    __syncthreads();

    float v0 = 0.f, v1 = 0.f;
#pragma unroll
    for (int c = 0; c < 5; ++c) { v0 += We[c] * att_edge[c]; v1 += We[5 + c] * att_edge[c]; }

    int base = blockIdx.x * EPB;
    for (int k = 0; k < EPT; ++k) {
        int e = base + k * TPB + t;
        if (e >= nE) continue;
        unsigned s = (unsigned)ei[e];
        unsigned d = (unsigned)ei[nE + e];
        float2 at = ((const float2*)ea)[e];
        unsigned dloc, sloc;
        unsigned bd = bucket_of(d, npb, inv_npb, &dloc);
        float a_s = apack[s].x;
        float a_d = apack[d].y;
        float z = a_s + a_d + at.x * v0 + at.y * v1;
        float l = z > 0.f ? z : NEG_SLOPE * z;
        float ev = __expf(l);
        int r = atomicAdd(&cD[bd], 1);
        payD[baseD[bd] + r] = make_int2((int)(s | (dloc << 18)), __float_as_int(ev));
        bool close = at.x < CONSUME_R;
        bool cell  = (at.y == 1.0f);
        if (close || cell) {
            unsigned bs = bucket_of(s, npb, inv_npb, &sloc);
            int r2 = atomicAdd(&cS[bs], 1);
            payS[baseS[bs] + r2] = sloc | (close ? (1u << 10) : 0u) | (cell ? (1u << 11) : 0u);
        }
    }
}

// ---------------------------------------------------------------------------
// Per-bucket accumulation in LDS (fp32), then one coalesced store.
// acc[node*6 + 0..4] = sum ev*hs, [5] = sum ev. cnt[node] = close | cell<<16.
// ---------------------------------------------------------------------------
__global__ __launch_bounds__(1024) void k_bucket(
    const int2* __restrict__ payD, const unsigned* __restrict__ payS,
    const int* __restrict__ startD, const int* __restrict__ startS,
    const uint4* __restrict__ hpack,
    float* __restrict__ accg, int* __restrict__ cntg, int n, unsigned npb)
{
    __shared__ float accf[MAXNPB * 6];
    __shared__ int   cnts[MAXNPB];
    int b = blockIdx.x, t = threadIdx.x;
    int nodes = min((int)npb, n - b * (int)npb);
    for (int j = t; j < (int)npb * 6; j += 1024) accf[j] = 0.f;
    for (int j = t; j < (int)npb;     j += 1024) cnts[j] = 0;
    __syncthreads();

    int s0 = startD[b], s1 = startD[b + 1];
    for (int i = s0 + t; i < s1; i += 1024) {
        int2 pl = payD[i];
        unsigned key = (unsigned)pl.x;
        float ev = __int_as_float(pl.y);
        unsigned src  = key & 0x3FFFFu;
        unsigned dloc = key >> 18;
        uint4 hp = hpack[src];
        float h0 = __uint_as_float(hp.x << 16);
        float h1 = __uint_as_float(hp.x & 0xFFFF0000u);
        float h2 = __uint_as_float(hp.y << 16);
        float h3 = __uint_as_float(hp.y & 0xFFFF0000u);
        float h4 = __uint_as_float(hp.z << 16);
        float* a = &accf[dloc * 6];
        atomicAdd(a + 0, ev * h0);
        atomicAdd(a + 1, ev * h1);
        atomicAdd(a + 2, ev * h2);
        atomicAdd(a + 3, ev * h3);
        atomicAdd(a + 4, ev * h4);
        atomicAdd(a + 5, ev);
    }
    __syncthreads();
    size_t gbase = (size_t)b * npb * 6;
    for (int j = t; j < nodes * 6; j += 1024) accg[gbase + j] = accf[j];

    int u0 = startS[b], u1 = startS[b + 1];
    for (int i = u0 + t; i < u1; i += 1024) {
        unsigned v = payS[i];
        unsigned sloc = v & 1023u;
        int add = (int)((v >> 10) & 1u) | (int)(((v >> 11) & 1u) << 16);
        atomicAdd(&cnts[sloc], add);
    }
    __syncthreads();
    for (int j = t; j < nodes; j += 1024) cntg[(size_t)b * npb + j] = cnts[j];
}

// ---------------------------------------------------------------------------
// Finalize: GAT out -> MLP -> physics; block-reduce 5 scalars.
// astride: 6 (fast path) or 8 (fallback). denom at +5 in both.
// ---------------------------------------------------------------------------
__global__ __launch_bounds__(256) void k_final(
    const float* __restrict__ x, const float* __restrict__ acc, int astride,
    const int* __restrict__ cnt,
    const float* __restrict__ gat_bias, const float* __restrict__ W1,
    const float* __restrict__ b1, const float* __restrict__ W2,
    const float* __restrict__ b2,
    float* __restrict__ out, float* __restrict__ scal, int n)
{
    int i = blockIdx.x * 256 + threadIdx.x;
    float part[5] = {0.f, 0.f, 0.f, 0.f, 0.f};

    if (i < n) {
        const float* a = acc + (size_t)i * astride;
        float inv = 1.0f / fmaxf(a[5], 1e-16f);
        float h[5];
#pragma unroll
        for (int c = 0; c < 5; ++c) h[c] = a[c] * inv + gat_bias[c];
        float tt[5];
#pragma unroll
        for (int c = 0; c < 5; ++c) {
            float s = b1[c];
#pragma unroll
            for (int k = 0; k < 5; ++k) s += h[k] * W1[k * 5 + c];
            tt[c] = fmaxf(s, 0.f);
        }
        float u0 = b2[0], u1 = b2[1];
#pragma unroll
        for (int k = 0; k < 5; ++k) { u0 += tt[k] * W2[k * 2]; u1 += tt[k] * W2[k * 2 + 1]; }
        u0 = fmaxf(u0, 0.f) * 2.f - 1.f;
        u1 = fmaxf(u1, 0.f) * 2.f - 1.f;

        float px = x[(size_t)i * 5],     py = x[(size_t)i * 5 + 1];
        float vx = x[(size_t)i * 5 + 2], vy = x[(size_t)i * 5 + 3];
        float ty = x[(size_t)i * 5 + 4];
        float mask = (ty == 1.0f) ? 1.0f : 0.0f;
        float nvx = fminf(fmaxf(vx + u0 * ACCEL_SCALE * mask, -MAX_VEL), MAX_VEL);
        float nvy = fminf(fmaxf(vy + u1 * ACCEL_SCALE * mask, -MAX_VEL), MAX_VEL);
        float npx = px + nvx, npy = py + nvy;

        out[(size_t)i * 5]     = npx;
        out[(size_t)i * 5 + 1] = npy;
        out[(size_t)i * 5 + 2] = nvx;
        out[(size_t)i * 5 + 3] = nvy;
        out[(size_t)i * 5 + 4] = ty;

        part[0] = fabsf(nvx);
        part[1] = fabsf(nvy);
        float bc = 0.f;
        if (fabsf(npx) > 1.0f) bc += logf(fabsf(npx) + 1e-6f);
        if (fabsf(npy) > 1.0f) bc += logf(fabsf(npy) + 1e-6f);
        part[2] = bc;
        int c = cnt[i];
        part[3] = (ty == 0.0f && (c & 0xffff) >= 3) ? 1.f : 0.f;
        part[4] = (ty == 1.0f && (c >> 16) < 1) ? 1.f : 0.f;
    }

    __shared__ float sm[4][5];
#pragma unroll
    for (int q = 0; q < 5; ++q)
#pragma unroll
        for (int off = 32; off > 0; off >>= 1)
            part[q] += __shfl_down(part[q], off);
    int lane = threadIdx.x & 63, wid = threadIdx.x >> 6;
    if (lane == 0)
#pragma unroll
        for (int q = 0; q < 5; ++q) sm[wid][q] = part[q];
    __syncthreads();
    if (threadIdx.x == 0) {
#pragma unroll
        for (int q = 0; q < 5; ++q) {
            float s = sm[0][q] + sm[1][q] + sm[2][q] + sm[3][q];
            unsafeAtomicAdd(scal + q, s);
        }
    }
}

__global__ void k_tail(const float* __restrict__ scal, float* __restrict__ out, int n)
{
    if (threadIdx.x == 0 && blockIdx.x == 0) {
        size_t base = (size_t)n * 5;
        float invn = 1.0f / (float)n;
        out[base + 0] = scal[0] * invn;
        out[base + 1] = scal[1] * invn;
        out[base + 2] = scal[2];
        out[base + 3] = scal[3];
        out[base + 4] = scal[4];
    }
}

// ------------------- fallback (round-1 atomic path) ------------------------
__global__ __launch_bounds__(256) void k_node_pre_fb(
    const float* __restrict__ x, const float* __restrict__ W,
    const float* __restrict__ att_src, const float* __restrict__ att_dst,
    float* __restrict__ npack, int n)
{
    int i = blockIdx.x * 256 + threadIdx.x;
    if (i >= n) return;
    float xr[5];
#pragma unroll
    for (int k = 0; k < 5; ++k) xr[k] = x[(size_t)i * 5 + k];
    float hs[5];
#pragma unroll
    for (int c = 0; c < 5; ++c) {
        float s = 0.f;
#pragma unroll
        for (int k = 0; k < 5; ++k) s += xr[k] * W[k * 5 + c];
        hs[c] = s;
    }
    float a_s = 0.f, a_d = 0.f;
#pragma unroll
    for (int c = 0; c < 5; ++c) { a_s += hs[c] * att_src[c]; a_d += hs[c] * att_dst[c]; }
    *(float4*)(npack + (size_t)i * 8)     = make_float4(hs[0], hs[1], hs[2], hs[3]);
    *(float4*)(npack + (size_t)i * 8 + 4) = make_float4(hs[4], a_s, a_d, 0.f);
}

__global__ __launch_bounds__(256) void k_edge_fb(
    const int* __restrict__ ei, const float* __restrict__ ea,
    const float* __restrict__ We, const float* __restrict__ att_edge,
    const float* __restrict__ npack, float* __restrict__ acc,
    int* __restrict__ cnt, int nE)
{
    int e = blockIdx.x * 256 + threadIdx.x;
    if (e >= nE) return;
    float v0 = 0.f, v1 = 0.f;
#pragma unroll
    for (int c = 0; c < 5; ++c) { v0 += We[c] * att_edge[c]; v1 += We[5 + c] * att_edge[c]; }
    int s = ei[e];
    int d = ei[nE + e];
    float2 at = *(const float2*)(ea + (size_t)e * 2);
    const float4 p0 = *(const float4*)(npack + (size_t)s * 8);
    const float2 p1 = *(const float2*)(npack + (size_t)s * 8 + 4);
    float a_dst_d = npack[(size_t)d * 8 + 6];
    float z = p1.y + a_dst_d + (at.x * v0 + at.y * v1);
    float l = z > 0.f ? z : NEG_SLOPE * z;
    float ev = __expf(l);
    float* ad = acc + (size_t)d * 8;
    unsafeAtomicAdd(ad + 0, ev * p0.x);
    unsafeAtomicAdd(ad + 1, ev * p0.y);
    unsafeAtomicAdd(ad + 2, ev * p0.z);
    unsafeAtomicAdd(ad + 3, ev * p0.w);
    unsafeAtomicAdd(ad + 4, ev * p1.x);
    unsafeAtomicAdd(ad + 5, ev);
    int cb = (at.x < CONSUME_R ? 1 : 0) | (at.y == 1.0f ? (1 << 16) : 0);
    if (cb) atomicAdd(cnt + s, cb);
}

// ---------------------------------------------------------------------------
extern "C" void kernel_launch(void* const* d_in, const int* in_sizes, int n_in,
                              void* d_out, int out_size, void* d_ws, size_t ws_size,
                              hipStream_t stream)
{
    const float* x        = (const float*)d_in[0];
    const int*   ei       = (const int*)  d_in[1];
    const float* ea       = (const float*)d_in[2];
    const float* W        = (const float*)d_in[3];
    const float* att_src  = (const float*)d_in[4];
    const float* att_dst  = (const float*)d_in[5];
    const float* We       = (const float*)d_in[6];
    const float* att_edge = (const float*)d_in[7];
    const float* gat_bias = (const float*)d_in[8];
    const float* W1       = (const float*)d_in[9];
    const float* b1       = (const float*)d_in[10];
    const float* W2       = (const float*)d_in[11];
    const float* b2       = (const float*)d_in[12];

    int n  = in_sizes[0] / 5;
    int nE = in_sizes[1] / 2;

    unsigned npb = (unsigned)((n + NBUCK - 1) / NBUCK);
    int NB = (nE + EPB - 1) / EPB;

    // fast-path workspace layout
    size_t o = 0;
    auto alloc = [&](size_t bytes) { size_t r = o; o = (o + bytes + 15) & ~15ULL; return r; };
    size_t off_apack = alloc((size_t)n * 8);
    size_t off_hpack = alloc((size_t)n * 16);
    size_t off_acc   = alloc((size_t)n * 24);
    size_t off_cnt   = alloc((size_t)n * 4);
    size_t off_scal  = alloc(64);
    size_t off_stD   = alloc((size_t)(NBUCK + 1) * 4);
    size_t off_stS   = alloc((size_t)(NBUCK + 1) * 4);
    size_t off_hist  = alloc((size_t)2 * NBUCK * NB * 4);
    size_t off_payD  = alloc((size_t)nE * 8);
    size_t off_payS  = alloc((size_t)nE * 4);
    size_t need = o;

    char* wsb = (char*)d_ws;
    bool fast = (ws_size >= need) && (n < (1 << 18)) && (npb <= MAXNPB);

    if (fast) {
        float2*   apack  = (float2*)(wsb + off_apack);
        uint4*    hpack  = (uint4*)(wsb + off_hpack);
        float*    acc    = (float*)(wsb + off_acc);
        int*      cnt    = (int*)(wsb + off_cnt);
        float*    scal   = (float*)(wsb + off_scal);
        int*      startD = (int*)(wsb + off_stD);
        int*      startS = (int*)(wsb + off_stS);
        int*      histG  = (int*)(wsb + off_hist);
        int2*     payD   = (int2*)(wsb + off_payD);
        unsigned* payS   = (unsigned*)(wsb + off_payS);
        float inv_npb = 1.0f / (float)npb;

        hipMemsetAsync(scal, 0, 64, stream);
        k_pre<<<(n + 255) / 256, 256, 0, stream>>>(x, W, att_src, att_dst, apack, hpack, n);
        k_hist<<<NB, TPB, 0, stream>>>(ei, ea, histG, NB, nE, npb, inv_npb);
        k_scan<<<1, 512, 0, stream>>>(histG, startD, startS, NB);
        k_scatter<<<NB, TPB, 0, stream>>>(ei, ea, apack, We, att_edge, histG,
                                          startD, startS, payD, payS, NB, nE, npb, inv_npb);
        k_bucket<<<NBUCK, 1024, 0, stream>>>(payD, payS, startD, startS, hpack,
                                             acc, cnt, n, npb);
        k_final<<<(n + 255) / 256, 256, 0, stream>>>(x, acc, 6, cnt, gat_bias, W1, b1,
                                                     W2, b2, (float*)d_out, scal, n);
        k_tail<<<1, 64, 0, stream>>>(scal, (float*)d_out, n);
    } else {
        // round-1 atomic fallback
        float* ws    = (float*)d_ws;
        float* npack = ws;
        float* acc   = ws + (size_t)n * 8;
        int*   cnt   = (int*)(acc + (size_t)n * 8);
        float* scal  = (float*)(cnt + n);
        size_t zbytes = ((size_t)n * 8 + (size_t)n + 8) * sizeof(float);
        hipMemsetAsync(acc, 0, zbytes, stream);
        k_node_pre_fb<<<(n + 255) / 256, 256, 0, stream>>>(x, W, att_src, att_dst, npack, n);
        k_edge_fb<<<(nE + 255) / 256, 256, 0, stream>>>(ei, ea, We, att_edge, npack,
                                                        acc, cnt, nE);
        k_final<<<(n + 255) / 256, 256, 0, stream>>>(x, acc, 8, cnt, gat_bias, W1, b1,
                                                     W2, b2, (float*)d_out, scal, n);
        k_tail<<<1, 64, 0, stream>>>(scal, (float*)d_out, n);
    }
}

// Round 3
// 948.272 us; speedup vs baseline: 4.7110x; 1.8959x over previous
//
#include <hip/hip_runtime.h>
#include <math.h>

#define NEG_SLOPE   0.2f
#define CONSUME_R   0.1f     // RADIUS*2
#define ACCEL_SCALE 0.01f
#define MAX_VEL     0.1f

#define NBUCK  256
#define TPB    256
#define EPT    16
#define EPB    (TPB*EPT)     // 4096 edges per block slice
#define MAXNPB 1024

// bucket id + local index for node v; npb = nodes per bucket
__device__ __forceinline__ unsigned bucket_of(unsigned v, unsigned npb, float inv_npb,
                                              unsigned* loc)
{
    unsigned b = (unsigned)((float)v * inv_npb);
    unsigned lo = b * npb;
    if (v < lo)            { --b; lo -= npb; }
    else if (v >= lo + npb){ ++b; lo += npb; }
    *loc = v - lo;
    return b;
}

// ---------------------------------------------------------------------------
// Node precompute: apack[i] = (a_src, a_dst) fp32; hpack[i] = hs bf16
// ---------------------------------------------------------------------------
__global__ __launch_bounds__(256) void k_pre(
    const float* __restrict__ x, const float* __restrict__ W,
    const float* __restrict__ att_src, const float* __restrict__ att_dst,
    float2* __restrict__ apack, uint4* __restrict__ hpack, int n)
{
    int i = blockIdx.x * 256 + threadIdx.x;
    if (i >= n) return;
    float xr[5];
#pragma unroll
    for (int k = 0; k < 5; ++k) xr[k] = x[(size_t)i * 5 + k];
    float hs[5];
#pragma unroll
    for (int c = 0; c < 5; ++c) {
        float s = 0.f;
#pragma unroll
        for (int k = 0; k < 5; ++k) s += xr[k] * W[k * 5 + c];
        hs[c] = s;
    }
    float a_s = 0.f, a_d = 0.f;
#pragma unroll
    for (int c = 0; c < 5; ++c) { a_s += hs[c] * att_src[c]; a_d += hs[c] * att_dst[c]; }
    apack[i] = make_float2(a_s, a_d);
    unsigned b[5];
#pragma unroll
    for (int c = 0; c < 5; ++c) {
        unsigned u = __float_as_uint(hs[c]);
        b[c] = (u + 0x7FFFu + ((u >> 16) & 1u)) >> 16;
    }
    hpack[i] = make_uint4(b[0] | (b[1] << 16), b[2] | (b[3] << 16), b[4], 0u);
}

// ---------------------------------------------------------------------------
// Single-pass binning: each block owns an EPB slice of payD/payS. Edges held
// in registers across {count -> scan -> rank+write}. Writes land inside the
// block's own 40KB region (L2-hot -> full-line eviction).
// payD = {src|dloc<<18, ev}. payS = ushort sloc|close<<10|cell<<11.
// dirD/dirS[b*NB+blk] = within-slice exclusive base (row NBUCK = total).
// ---------------------------------------------------------------------------
__global__ __launch_bounds__(TPB) void k_scatter1(
    const int* __restrict__ ei, const float* __restrict__ ea,
    const float2* __restrict__ apack,
    const float* __restrict__ We, const float* __restrict__ att_edge,
    int2* __restrict__ payD, unsigned short* __restrict__ payS,
    int* __restrict__ dirD, int* __restrict__ dirS,
    int NB, int nE, unsigned npb, float inv_npb)
{
    __shared__ int cD[NBUCK], cS[NBUCK], baseD[NBUCK], baseS[NBUCK];
    __shared__ int wsumD[4], wsumS[4];
    int t = threadIdx.x, blk = blockIdx.x;
    cD[t] = 0; cS[t] = 0;
    __syncthreads();

    float v0 = 0.f, v1 = 0.f;
#pragma unroll
    for (int c = 0; c < 5; ++c) { v0 += We[c] * att_edge[c]; v1 += We[5 + c] * att_edge[c]; }

    int base = blk * EPB;
    int key[EPT]; float evr[EPT]; int pk[EPT];

    // pass A: load, compute, count
#pragma unroll
    for (int k = 0; k < EPT; ++k) {
        int e = base + k * TPB + t;
        key[k] = -1;
        if (e < nE) {
            unsigned s = (unsigned)ei[e];
            unsigned d = (unsigned)ei[nE + e];
            float2 at = ((const float2*)ea)[e];
            unsigned dloc, sloc;
            unsigned bd = bucket_of(d, npb, inv_npb, &dloc);
            unsigned bs = bucket_of(s, npb, inv_npb, &sloc);
            float z = apack[s].x + apack[d].y + at.x * v0 + at.y * v1;
            float l = z > 0.f ? z : NEG_SLOPE * z;
            evr[k] = __expf(l);
            key[k] = (int)(s | (dloc << 18));
            bool close = at.x < CONSUME_R;
            bool cell  = (at.y == 1.0f);
            unsigned srec = sloc | (close ? 0x400u : 0u) | (cell ? 0x800u : 0u);
            pk[k] = (int)(bd | (bs << 8) | (srec << 16));
            atomicAdd(&cD[bd], 1);
            if (close || cell) atomicAdd(&cS[bs], 1);
        }
    }
    __syncthreads();

    // block-wide exclusive scan of the 256 bucket counters (wave scans + fix)
    int xD = cD[t], xS = cS[t];
    int origD = xD, origS = xS;
#pragma unroll
    for (int off = 1; off < 64; off <<= 1) {
        int yD = __shfl_up(xD, off);
        int yS = __shfl_up(xS, off);
        if ((t & 63) >= off) { xD += yD; xS += yS; }
    }
    if ((t & 63) == 63) { wsumD[t >> 6] = xD; wsumS[t >> 6] = xS; }
    __syncthreads();
    int addD = 0, addS = 0;
    for (int w = 0; w < (t >> 6); ++w) { addD += wsumD[w]; addS += wsumS[w]; }
    baseD[t] = xD + addD - origD;
    baseS[t] = xS + addS - origS;
    dirD[(size_t)t * NB + blk] = baseD[t];
    dirS[(size_t)t * NB + blk] = baseS[t];
    if (t == 0) {
        dirD[(size_t)NBUCK * NB + blk] = wsumD[0] + wsumD[1] + wsumD[2] + wsumD[3];
        dirS[(size_t)NBUCK * NB + blk] = wsumS[0] + wsumS[1] + wsumS[2] + wsumS[3];
    }
    cD[t] = 0; cS[t] = 0;
    __syncthreads();

    // pass B: rank + write into own slice
    size_t sliceD = (size_t)blk * EPB;
#pragma unroll
    for (int k = 0; k < EPT; ++k) {
        if (key[k] >= 0) {
            unsigned p = (unsigned)pk[k];
            unsigned bd = p & 0xFFu, bs = (p >> 8) & 0xFFu, srec = p >> 16;
            int r = atomicAdd(&cD[bd], 1);
            payD[sliceD + baseD[bd] + r] = make_int2(key[k], __float_as_int(evr[k]));
            if (srec & 0xC00u) {
                int r2 = atomicAdd(&cS[bs], 1);
                payS[sliceD + baseS[bs] + r2] = (unsigned short)srec;
            }
        }
    }
}

// ---------------------------------------------------------------------------
// Per-bucket accumulate (LDS, stride 7) + fused finalize (MLP/physics/scalars)
// ---------------------------------------------------------------------------
__global__ __launch_bounds__(1024) void k_bucket2(
    const int2* __restrict__ payD, const unsigned short* __restrict__ payS,
    const int* __restrict__ dirD, const int* __restrict__ dirS,
    const uint4* __restrict__ hpack, const float* __restrict__ x,
    int NB, int n, unsigned npb,
    const float* __restrict__ gat_bias, const float* __restrict__ W1,
    const float* __restrict__ b1, const float* __restrict__ W2,
    const float* __restrict__ b2,
    float* __restrict__ out, float* __restrict__ scal)
{
    __shared__ float accf[MAXNPB * 7];
    __shared__ int   cnts[MAXNPB];
    int b = blockIdx.x, t = threadIdx.x;
    for (int j = t; j < (int)npb * 7; j += 1024) accf[j] = 0.f;
    for (int j = t; j < (int)npb;     j += 1024) cnts[j] = 0;
    __syncthreads();

    int wave = t >> 6, lane = t & 63;
    int half = lane >> 5, l32 = lane & 31;   // 2 runs per wave

    const int* rs = dirD + (size_t)b * NB;
    const int* re = dirD + (size_t)(b + 1) * NB;
    for (int blk = wave * 2 + half; blk < NB; blk += 32) {
        int st = rs[blk], en = re[blk];
        size_t sbase = (size_t)blk * EPB;
        for (int i = st + l32; i < en; i += 32) {
            int2 pl = payD[sbase + i];
            unsigned key = (unsigned)pl.x;
            float ev = __int_as_float(pl.y);
            unsigned src  = key & 0x3FFFFu;
            unsigned dloc = (key >> 18) & 0x3FFu;
            uint4 hp = hpack[src];
            float h0 = __uint_as_float(hp.x << 16);
            float h1 = __uint_as_float(hp.x & 0xFFFF0000u);
            float h2 = __uint_as_float(hp.y << 16);
            float h3 = __uint_as_float(hp.y & 0xFFFF0000u);
            float h4 = __uint_as_float(hp.z << 16);
            float* a = &accf[dloc * 7];
            atomicAdd(a + 0, ev * h0);
            atomicAdd(a + 1, ev * h1);
            atomicAdd(a + 2, ev * h2);
            atomicAdd(a + 3, ev * h3);
            atomicAdd(a + 4, ev * h4);
            atomicAdd(a + 5, ev);
        }
    }
    const int* qs = dirS + (size_t)b * NB;
    const int* qe = dirS + (size_t)(b + 1) * NB;
    for (int blk = wave * 2 + half; blk < NB; blk += 32) {
        int st = qs[blk], en = qe[blk];
        size_t sbase = (size_t)blk * EPB;
        for (int i = st + l32; i < en; i += 32) {
            unsigned srec = payS[sbase + i];
            int add = (int)((srec >> 10) & 1u) | (int)(((srec >> 11) & 1u) << 16);
            atomicAdd(&cnts[srec & 0x3FFu], add);
        }
    }
    __syncthreads();

    // fused finalize for this bucket's nodes
    int first = b * (int)npb;
    int nodes = n - first; if (nodes > (int)npb) nodes = (int)npb; if (nodes < 0) nodes = 0;
    float part[5] = {0.f, 0.f, 0.f, 0.f, 0.f};
    if (t < nodes) {
        int i = first + t;
        const float* a = &accf[t * 7];
        float inv = 1.0f / fmaxf(a[5], 1e-16f);
        float h[5];
#pragma unroll
        for (int c = 0; c < 5; ++c) h[c] = a[c] * inv + gat_bias[c];
        float tt[5];
#pragma unroll
        for (int c = 0; c < 5; ++c) {
            float s = b1[c];
#pragma unroll
            for (int k = 0; k < 5; ++k) s += h[k] * W1[k * 5 + c];
            tt[c] = fmaxf(s, 0.f);
        }
        float u0 = b2[0], u1 = b2[1];
#pragma unroll
        for (int k = 0; k < 5; ++k) { u0 += tt[k] * W2[k * 2]; u1 += tt[k] * W2[k * 2 + 1]; }
        u0 = fmaxf(u0, 0.f) * 2.f - 1.f;
        u1 = fmaxf(u1, 0.f) * 2.f - 1.f;

        float px = x[(size_t)i * 5],     py = x[(size_t)i * 5 + 1];
        float vx = x[(size_t)i * 5 + 2], vy = x[(size_t)i * 5 + 3];
        float ty = x[(size_t)i * 5 + 4];
        float mask = (ty == 1.0f) ? 1.0f : 0.0f;
        float nvx = fminf(fmaxf(vx + u0 * ACCEL_SCALE * mask, -MAX_VEL), MAX_VEL);
        float nvy = fminf(fmaxf(vy + u1 * ACCEL_SCALE * mask, -MAX_VEL), MAX_VEL);
        float npx = px + nvx, npy = py + nvy;

        out[(size_t)i * 5]     = npx;
        out[(size_t)i * 5 + 1] = npy;
        out[(size_t)i * 5 + 2] = nvx;
        out[(size_t)i * 5 + 3] = nvy;
        out[(size_t)i * 5 + 4] = ty;

        part[0] = fabsf(nvx);
        part[1] = fabsf(nvy);
        float bc = 0.f;
        if (fabsf(npx) > 1.0f) bc += logf(fabsf(npx) + 1e-6f);
        if (fabsf(npy) > 1.0f) bc += logf(fabsf(npy) + 1e-6f);
        part[2] = bc;
        int c = cnts[t];
        part[3] = (ty == 0.0f && (c & 0xffff) >= 3) ? 1.f : 0.f;
        part[4] = (ty == 1.0f && (c >> 16) < 1) ? 1.f : 0.f;
    }

    __shared__ float sm[16][5];
#pragma unroll
    for (int q = 0; q < 5; ++q)
#pragma unroll
        for (int off = 32; off > 0; off >>= 1)
            part[q] += __shfl_down(part[q], off);
    if (lane == 0)
#pragma unroll
        for (int q = 0; q < 5; ++q) sm[wave][q] = part[q];
    __syncthreads();
    if (t == 0) {
#pragma unroll
        for (int q = 0; q < 5; ++q) {
            float s = 0.f;
#pragma unroll
            for (int w = 0; w < 16; ++w) s += sm[w][q];
            unsafeAtomicAdd(scal + q, s);
        }
    }
}

__global__ void k_tail(const float* __restrict__ scal, float* __restrict__ out, int n)
{
    if (threadIdx.x == 0 && blockIdx.x == 0) {
        size_t base = (size_t)n * 5;
        float invn = 1.0f / (float)n;
        out[base + 0] = scal[0] * invn;
        out[base + 1] = scal[1] * invn;
        out[base + 2] = scal[2];
        out[base + 3] = scal[3];
        out[base + 4] = scal[4];
    }
}

// ------------------- fallback (round-1 atomic path) ------------------------
__global__ __launch_bounds__(256) void k_node_pre_fb(
    const float* __restrict__ x, const float* __restrict__ W,
    const float* __restrict__ att_src, const float* __restrict__ att_dst,
    float* __restrict__ npack, int n)
{
    int i = blockIdx.x * 256 + threadIdx.x;
    if (i >= n) return;
    float xr[5];
#pragma unroll
    for (int k = 0; k < 5; ++k) xr[k] = x[(size_t)i * 5 + k];
    float hs[5];
#pragma unroll
    for (int c = 0; c < 5; ++c) {
        float s = 0.f;
#pragma unroll
        for (int k = 0; k < 5; ++k) s += xr[k] * W[k * 5 + c];
        hs[c] = s;
    }
    float a_s = 0.f, a_d = 0.f;
#pragma unroll
    for (int c = 0; c < 5; ++c) { a_s += hs[c] * att_src[c]; a_d += hs[c] * att_dst[c]; }
    *(float4*)(npack + (size_t)i * 8)     = make_float4(hs[0], hs[1], hs[2], hs[3]);
    *(float4*)(npack + (size_t)i * 8 + 4) = make_float4(hs[4], a_s, a_d, 0.f);
}

__global__ __launch_bounds__(256) void k_edge_fb(
    const int* __restrict__ ei, const float* __restrict__ ea,
    const float* __restrict__ We, const float* __restrict__ att_edge,
    const float* __restrict__ npack, float* __restrict__ acc,
    int* __restrict__ cnt, int nE)
{
    int e = blockIdx.x * 256 + threadIdx.x;
    if (e >= nE) return;
    float v0 = 0.f, v1 = 0.f;
#pragma unroll
    for (int c = 0; c < 5; ++c) { v0 += We[c] * att_edge[c]; v1 += We[5 + c] * att_edge[c]; }
    int s = ei[e];
    int d = ei[nE + e];
    float2 at = *(const float2*)(ea + (size_t)e * 2);
    const float4 p0 = *(const float4*)(npack + (size_t)s * 8);
    const float2 p1 = *(const float2*)(npack + (size_t)s * 8 + 4);
    float a_dst_d = npack[(size_t)d * 8 + 6];
    float z = p1.y + a_dst_d + (at.x * v0 + at.y * v1);
    float l = z > 0.f ? z : NEG_SLOPE * z;
    float ev = __expf(l);
    float* ad = acc + (size_t)d * 8;
    unsafeAtomicAdd(ad + 0, ev * p0.x);
    unsafeAtomicAdd(ad + 1, ev * p0.y);
    unsafeAtomicAdd(ad + 2, ev * p0.z);
    unsafeAtomicAdd(ad + 3, ev * p0.w);
    unsafeAtomicAdd(ad + 4, ev * p1.x);
    unsafeAtomicAdd(ad + 5, ev);
    int cb = (at.x < CONSUME_R ? 1 : 0) | (at.y == 1.0f ? (1 << 16) : 0);
    if (cb) atomicAdd(cnt + s, cb);
}

__global__ __launch_bounds__(256) void k_final_fb(
    const float* __restrict__ x, const float* __restrict__ acc,
    const int* __restrict__ cnt,
    const float* __restrict__ gat_bias, const float* __restrict__ W1,
    const float* __restrict__ b1, const float* __restrict__ W2,
    const float* __restrict__ b2,
    float* __restrict__ out, float* __restrict__ scal, int n)
{
    int i = blockIdx.x * 256 + threadIdx.x;
    float part[5] = {0.f, 0.f, 0.f, 0.f, 0.f};
    if (i < n) {
        const float* a = acc + (size_t)i * 8;
        float inv = 1.0f / fmaxf(a[5], 1e-16f);
        float h[5];
#pragma unroll
        for (int c = 0; c < 5; ++c) h[c] = a[c] * inv + gat_bias[c];
        float tt[5];
#pragma unroll
        for (int c = 0; c < 5; ++c) {
            float s = b1[c];
#pragma unroll
            for (int k = 0; k < 5; ++k) s += h[k] * W1[k * 5 + c];
            tt[c] = fmaxf(s, 0.f);
        }
        float u0 = b2[0], u1 = b2[1];
#pragma unroll
        for (int k = 0; k < 5; ++k) { u0 += tt[k] * W2[k * 2]; u1 += tt[k] * W2[k * 2 + 1]; }
        u0 = fmaxf(u0, 0.f) * 2.f - 1.f;
        u1 = fmaxf(u1, 0.f) * 2.f - 1.f;
        float px = x[(size_t)i * 5],     py = x[(size_t)i * 5 + 1];
        float vx = x[(size_t)i * 5 + 2], vy = x[(size_t)i * 5 + 3];
        float ty = x[(size_t)i * 5 + 4];
        float mask = (ty == 1.0f) ? 1.0f : 0.0f;
        float nvx = fminf(fmaxf(vx + u0 * ACCEL_SCALE * mask, -MAX_VEL), MAX_VEL);
        float nvy = fminf(fmaxf(vy + u1 * ACCEL_SCALE * mask, -MAX_VEL), MAX_VEL);
        float npx = px + nvx, npy = py + nvy;
        out[(size_t)i * 5]     = npx;
        out[(size_t)i * 5 + 1] = npy;
        out[(size_t)i * 5 + 2] = nvx;
        out[(size_t)i * 5 + 3] = nvy;
        out[(size_t)i * 5 + 4] = ty;
        part[0] = fabsf(nvx);
        part[1] = fabsf(nvy);
        float bc = 0.f;
        if (fabsf(npx) > 1.0f) bc += logf(fabsf(npx) + 1e-6f);
        if (fabsf(npy) > 1.0f) bc += logf(fabsf(npy) + 1e-6f);
        part[2] = bc;
        int c = cnt[i];
        part[3] = (ty == 0.0f && (c & 0xffff) >= 3) ? 1.f : 0.f;
        part[4] = (ty == 1.0f && (c >> 16) < 1) ? 1.f : 0.f;
    }
    __shared__ float sm[4][5];
#pragma unroll
    for (int q = 0; q < 5; ++q)
#pragma unroll
        for (int off = 32; off > 0; off >>= 1)
            part[q] += __shfl_down(part[q], off);
    int lane = threadIdx.x & 63, wid = threadIdx.x >> 6;
    if (lane == 0)
#pragma unroll
        for (int q = 0; q < 5; ++q) sm[wid][q] = part[q];
    __syncthreads();
    if (threadIdx.x == 0) {
#pragma unroll
        for (int q = 0; q < 5; ++q)
            unsafeAtomicAdd(scal + q, sm[0][q] + sm[1][q] + sm[2][q] + sm[3][q]);
    }
}

// ---------------------------------------------------------------------------
extern "C" void kernel_launch(void* const* d_in, const int* in_sizes, int n_in,
                              void* d_out, int out_size, void* d_ws, size_t ws_size,
                              hipStream_t stream)
{
    const float* x        = (const float*)d_in[0];
    const int*   ei       = (const int*)  d_in[1];
    const float* ea       = (const float*)d_in[2];
    const float* W        = (const float*)d_in[3];
    const float* att_src  = (const float*)d_in[4];
    const float* att_dst  = (const float*)d_in[5];
    const float* We       = (const float*)d_in[6];
    const float* att_edge = (const float*)d_in[7];
    const float* gat_bias = (const float*)d_in[8];
    const float* W1       = (const float*)d_in[9];
    const float* b1       = (const float*)d_in[10];
    const float* W2       = (const float*)d_in[11];
    const float* b2       = (const float*)d_in[12];

    int n  = in_sizes[0] / 5;
    int nE = in_sizes[1] / 2;

    unsigned npb = (unsigned)((n + NBUCK - 1) / NBUCK);
    int NB = (nE + EPB - 1) / EPB;

    size_t o = 0;
    auto alloc = [&](size_t bytes) { size_t r = o; o = (o + bytes + 63) & ~63ULL; return r; };
    size_t off_apack = alloc((size_t)n * 8);
    size_t off_hpack = alloc((size_t)n * 16);
    size_t off_scal  = alloc(64);
    size_t off_dirD  = alloc((size_t)(NBUCK + 1) * NB * 4);
    size_t off_dirS  = alloc((size_t)(NBUCK + 1) * NB * 4);
    size_t off_payD  = alloc((size_t)NB * EPB * 8);
    size_t off_payS  = alloc((size_t)NB * EPB * 2);
    size_t need = o;

    char* wsb = (char*)d_ws;
    bool fast = (ws_size >= need) && (n < (1 << 18)) && (npb <= MAXNPB);

    if (fast) {
        float2*         apack = (float2*)(wsb + off_apack);
        uint4*          hpack = (uint4*)(wsb + off_hpack);
        float*          scal  = (float*)(wsb + off_scal);
        int*            dirD  = (int*)(wsb + off_dirD);
        int*            dirS  = (int*)(wsb + off_dirS);
        int2*           payD  = (int2*)(wsb + off_payD);
        unsigned short* payS  = (unsigned short*)(wsb + off_payS);
        float inv_npb = 1.0f / (float)npb;

        hipMemsetAsync(scal, 0, 64, stream);
        k_pre<<<(n + 255) / 256, 256, 0, stream>>>(x, W, att_src, att_dst, apack, hpack, n);
        k_scatter1<<<NB, TPB, 0, stream>>>(ei, ea, apack, We, att_edge,
                                           payD, payS, dirD, dirS, NB, nE, npb, inv_npb);
        k_bucket2<<<NBUCK, 1024, 0, stream>>>(payD, payS, dirD, dirS, hpack, x,
                                              NB, n, npb, gat_bias, W1, b1, W2, b2,
                                              (float*)d_out, scal);
        k_tail<<<1, 64, 0, stream>>>(scal, (float*)d_out, n);
    } else {
        float* ws    = (float*)d_ws;
        float* npack = ws;
        float* acc   = ws + (size_t)n * 8;
        int*   cnt   = (int*)(acc + (size_t)n * 8);
        float* scal  = (float*)(cnt + n);
        size_t zbytes = ((size_t)n * 8 + (size_t)n + 8) * sizeof(float);
        hipMemsetAsync(acc, 0, zbytes, stream);
        k_node_pre_fb<<<(n + 255) / 256, 256, 0, stream>>>(x, W, att_src, att_dst, npack, n);
        k_edge_fb<<<(nE + 255) / 256, 256, 0, stream>>>(ei, ea, We, att_edge, npack,
                                                        acc, cnt, nE);
        k_final_fb<<<(n + 255) / 256, 256, 0, stream>>>(x, acc, cnt, gat_bias, W1, b1,
                                                        W2, b2, (float*)d_out, scal, n);
        k_tail<<<1, 64, 0, stream>>>(scal, (float*)d_out, n);
    }
}

// Round 4
// 874.431 us; speedup vs baseline: 5.1088x; 1.0844x over previous
//
#include <hip/hip_runtime.h>
#include <math.h>

#define NEG_SLOPE   0.2f
#define CONSUME_R   0.1f     // RADIUS*2
#define ACCEL_SCALE 0.01f
#define MAX_VEL     0.1f

#define NBUCK  256
#define TPB    256
#define EPT    16
#define EPB    (TPB*EPT)     // 4096 edges per block slice
#define MAXNPB 1024
#define MAXSPG 800

typedef float v2f __attribute__((ext_vector_type(2)));
typedef int   v2i __attribute__((ext_vector_type(2)));

__device__ __forceinline__ unsigned bucket_of(unsigned v, unsigned npb, float inv_npb,
                                              unsigned* loc)
{
    unsigned b = (unsigned)((float)v * inv_npb);
    unsigned lo = b * npb;
    if (v < lo)            { --b; lo -= npb; }
    else if (v >= lo + npb){ ++b; lo += npb; }
    *loc = v - lo;
    return b;
}

// ---------------------------------------------------------------------------
// Node precompute: aS/aD fp32 arrays (4B gathers), hpack = hs bf16 (16B)
// ---------------------------------------------------------------------------
__global__ __launch_bounds__(256) void k_pre(
    const float* __restrict__ x, const float* __restrict__ W,
    const float* __restrict__ att_src, const float* __restrict__ att_dst,
    float* __restrict__ aS, float* __restrict__ aD, uint4* __restrict__ hpack, int n)
{
    int i = blockIdx.x * 256 + threadIdx.x;
    if (i >= n) return;
    float xr[5];
#pragma unroll
    for (int k = 0; k < 5; ++k) xr[k] = x[(size_t)i * 5 + k];
    float hs[5];
#pragma unroll
    for (int c = 0; c < 5; ++c) {
        float s = 0.f;
#pragma unroll
        for (int k = 0; k < 5; ++k) s += xr[k] * W[k * 5 + c];
        hs[c] = s;
    }
    float a_s = 0.f, a_d = 0.f;
#pragma unroll
    for (int c = 0; c < 5; ++c) { a_s += hs[c] * att_src[c]; a_d += hs[c] * att_dst[c]; }
    aS[i] = a_s; aD[i] = a_d;
    unsigned b[5];
#pragma unroll
    for (int c = 0; c < 5; ++c) {
        unsigned u = __float_as_uint(hs[c]);
        b[c] = (u + 0x7FFFu + ((u >> 16) & 1u)) >> 16;
    }
    hpack[i] = make_uint4(b[0] | (b[1] << 16), b[2] | (b[3] << 16), b[4], 0u);
}

// ---------------------------------------------------------------------------
// Phase 1: single-pass binning into block-owned slices.
// payD = {src|dloc<<18, partial_logit (aS[s] + edge term)}  -- exp deferred.
// payS = ushort sloc|close<<10|cell<<11.
// dir[bucket][slice] = within-slice exclusive base (row NBUCK = slice total).
// ---------------------------------------------------------------------------
__global__ __launch_bounds__(TPB) void k_scatter1(
    const int* __restrict__ ei, const float* __restrict__ ea,
    const float* __restrict__ aS,
    const float* __restrict__ We, const float* __restrict__ att_edge,
    int2* __restrict__ payD, unsigned short* __restrict__ payS,
    int* __restrict__ dirD, int* __restrict__ dirS,
    int NB, int nE, unsigned npb, float inv_npb)
{
    __shared__ int cD[NBUCK], cS[NBUCK], baseD[NBUCK], baseS[NBUCK];
    __shared__ int wsumD[4], wsumS[4];
    int t = threadIdx.x, blk = blockIdx.x;
    cD[t] = 0; cS[t] = 0;
    __syncthreads();

    float v0 = 0.f, v1 = 0.f;
#pragma unroll
    for (int c = 0; c < 5; ++c) { v0 += We[c] * att_edge[c]; v1 += We[5 + c] * att_edge[c]; }

    int base = blk * EPB;
    int key[EPT]; float pv[EPT]; int pk[EPT];

    // pass A: load (nontemporal streams), one aS gather, count buckets
#pragma unroll
    for (int k = 0; k < EPT; ++k) {
        int e = base + k * TPB + t;
        key[k] = -1;
        if (e < nE) {
            unsigned s = (unsigned)__builtin_nontemporal_load(ei + e);
            unsigned d = (unsigned)__builtin_nontemporal_load(ei + nE + e);
            v2f at = __builtin_nontemporal_load((const v2f*)ea + e);
            unsigned dloc, sloc;
            unsigned bd = bucket_of(d, npb, inv_npb, &dloc);
            unsigned bs = bucket_of(s, npb, inv_npb, &sloc);
            pv[k] = aS[s] + at.x * v0 + at.y * v1;
            key[k] = (int)(s | (dloc << 18));
            bool close = at.x < CONSUME_R;
            bool cell  = (at.y == 1.0f);
            unsigned srec = sloc | (close ? 0x400u : 0u) | (cell ? 0x800u : 0u);
            pk[k] = (int)(bd | (bs << 8) | (srec << 16));
            atomicAdd(&cD[bd], 1);
            if (close || cell) atomicAdd(&cS[bs], 1);
        }
    }
    __syncthreads();

    // block-wide exclusive scan of 256 bucket counters
    int xD = cD[t], xS = cS[t];
    int origD = xD, origS = xS;
#pragma unroll
    for (int off = 1; off < 64; off <<= 1) {
        int yD = __shfl_up(xD, off);
        int yS = __shfl_up(xS, off);
        if ((t & 63) >= off) { xD += yD; xS += yS; }
    }
    if ((t & 63) == 63) { wsumD[t >> 6] = xD; wsumS[t >> 6] = xS; }
    __syncthreads();
    int addD = 0, addS = 0;
    for (int w = 0; w < (t >> 6); ++w) { addD += wsumD[w]; addS += wsumS[w]; }
    baseD[t] = xD + addD - origD;
    baseS[t] = xS + addS - origS;
    dirD[(size_t)t * NB + blk] = baseD[t];
    dirS[(size_t)t * NB + blk] = baseS[t];
    if (t == 0) {
        dirD[(size_t)NBUCK * NB + blk] = wsumD[0] + wsumD[1] + wsumD[2] + wsumD[3];
        dirS[(size_t)NBUCK * NB + blk] = wsumS[0] + wsumS[1] + wsumS[2] + wsumS[3];
    }
    cD[t] = 0; cS[t] = 0;
    __syncthreads();

    // pass B: rank + write into own 32KB slice (L2-merged, normal stores)
    size_t sliceD = (size_t)blk * EPB;
#pragma unroll
    for (int k = 0; k < EPT; ++k) {
        if (key[k] >= 0) {
            unsigned p = (unsigned)pk[k];
            unsigned bd = p & 0xFFu, bs = (p >> 8) & 0xFFu, srec = p >> 16;
            int r = atomicAdd(&cD[bd], 1);
            payD[sliceD + baseD[bd] + r] = make_int2(key[k], __float_as_int(pv[k]));
            if (srec & 0xC00u) {
                int r2 = atomicAdd(&cS[bs], 1);
                payS[sliceD + baseS[bs] + r2] = (unsigned short)srec;
            }
        }
    }
}

// ---------------------------------------------------------------------------
// Phase 2: per (bucket, slice-group) block. Run directory + aD in LDS.
// 16-lane groups walk runs; exp computed here; 6 LDS atomics/edge.
// Partial results -> accp[g][node][6], cntp[g][node].
// ---------------------------------------------------------------------------
__global__ __launch_bounds__(1024) void k_accum(
    const int2* __restrict__ payD, const unsigned short* __restrict__ payS,
    const int* __restrict__ dirD, const int* __restrict__ dirS,
    const uint4* __restrict__ hpack, const float* __restrict__ aD,
    float* __restrict__ accp, int* __restrict__ cntp,
    int NB, int G, int SPG, int n, unsigned npb)
{
    __shared__ float accf[MAXNPB * 6];
    __shared__ int   cnts[MAXNPB];
    __shared__ float aDl[MAXNPB];
    __shared__ int   stD[MAXSPG], enD[MAXSPG], stS[MAXSPG], enS[MAXSPG];

    int b = blockIdx.x & (NBUCK - 1);
    int g = blockIdx.x >> 8;
    int t = threadIdx.x;
    int s0 = g * SPG, s1 = min(NB, s0 + SPG), ns = s1 - s0;
    int first = b * (int)npb;
    int nodes = n - first; if (nodes > (int)npb) nodes = (int)npb; if (nodes < 0) nodes = 0;

    for (int j = t; j < (int)npb * 6; j += 1024) accf[j] = 0.f;
    for (int j = t; j < (int)npb;     j += 1024) cnts[j] = 0;
    for (int j = t; j < nodes;        j += 1024) aDl[j] = aD[first + j];
    for (int j = t; j < ns; j += 1024) {
        stD[j] = dirD[(size_t)b * NB + s0 + j];
        enD[j] = dirD[(size_t)(b + 1) * NB + s0 + j];
        stS[j] = dirS[(size_t)b * NB + s0 + j];
        enS[j] = dirS[(size_t)(b + 1) * NB + s0 + j];
    }
    __syncthreads();

    int q = t >> 4, l16 = t & 15;          // 64 groups of 16 lanes
    for (int i = q; i < ns; i += 64) {
        size_t sbase = (size_t)(s0 + i) * EPB;
        int st = stD[i], en = enD[i];
        for (int j = st + l16; j < en; j += 16) {
            v2i pl = __builtin_nontemporal_load((const v2i*)payD + sbase + j);
            unsigned key = (unsigned)pl.x;
            float partial = __int_as_float(pl.y);
            unsigned src  = key & 0x3FFFFu;
            unsigned dloc = (key >> 18) & 0x3FFu;
            float z = partial + aDl[dloc];
            float l = z > 0.f ? z : NEG_SLOPE * z;
            float ev = __expf(l);
            uint4 hp = hpack[src];
            float h0 = __uint_as_float(hp.x << 16);
            float h1 = __uint_as_float(hp.x & 0xFFFF0000u);
            float h2 = __uint_as_float(hp.y << 16);
            float h3 = __uint_as_float(hp.y & 0xFFFF0000u);
            float h4 = __uint_as_float(hp.z << 16);
            float* a = &accf[dloc * 6];
            atomicAdd(a + 0, ev * h0);
            atomicAdd(a + 1, ev * h1);
            atomicAdd(a + 2, ev * h2);
            atomicAdd(a + 3, ev * h3);
            atomicAdd(a + 4, ev * h4);
            atomicAdd(a + 5, ev);
        }
    }
    for (int i = q; i < ns; i += 64) {
        size_t sbase = (size_t)(s0 + i) * EPB;
        int st = stS[i], en = enS[i];
        for (int j = st + l16; j < en; j += 16) {
            unsigned srec = __builtin_nontemporal_load(payS + sbase + j);
            int add = (int)((srec >> 10) & 1u) | (int)(((srec >> 11) & 1u) << 16);
            atomicAdd(&cnts[srec & 0x3FFu], add);
        }
    }
    __syncthreads();

    size_t obase = ((size_t)g * n + first) * 6;
    for (int j = t; j < nodes * 6; j += 1024) accp[obase + j] = accf[j];
    for (int j = t; j < nodes;     j += 1024) cntp[(size_t)g * n + first + j] = cnts[j];
}

// ---------------------------------------------------------------------------
// Finalize: merge G partials, MLP, physics, scalar block-reduction
// ---------------------------------------------------------------------------
__global__ __launch_bounds__(256) void k_final(
    const float* __restrict__ x, const float* __restrict__ accp,
    const int* __restrict__ cntp, int G,
    const float* __restrict__ gat_bias, const float* __restrict__ W1,
    const float* __restrict__ b1, const float* __restrict__ W2,
    const float* __restrict__ b2,
    float* __restrict__ out, float* __restrict__ scal, int n)
{
    int i = blockIdx.x * 256 + threadIdx.x;
    float part[5] = {0.f, 0.f, 0.f, 0.f, 0.f};

    if (i < n) {
        float a[6] = {0.f, 0.f, 0.f, 0.f, 0.f, 0.f};
        int c = 0;
        for (int g = 0; g < G; ++g) {
            const float* p = accp + ((size_t)g * n + i) * 6;
#pragma unroll
            for (int k = 0; k < 6; ++k) a[k] += p[k];
            c += cntp[(size_t)g * n + i];
        }
        float inv = 1.0f / fmaxf(a[5], 1e-16f);
        float h[5];
#pragma unroll
        for (int k = 0; k < 5; ++k) h[k] = a[k] * inv + gat_bias[k];
        float tt[5];
#pragma unroll
        for (int cc = 0; cc < 5; ++cc) {
            float s = b1[cc];
#pragma unroll
            for (int k = 0; k < 5; ++k) s += h[k] * W1[k * 5 + cc];
            tt[cc] = fmaxf(s, 0.f);
        }
        float u0 = b2[0], u1 = b2[1];
#pragma unroll
        for (int k = 0; k < 5; ++k) { u0 += tt[k] * W2[k * 2]; u1 += tt[k] * W2[k * 2 + 1]; }
        u0 = fmaxf(u0, 0.f) * 2.f - 1.f;
        u1 = fmaxf(u1, 0.f) * 2.f - 1.f;

        float px = x[(size_t)i * 5],     py = x[(size_t)i * 5 + 1];
        float vx = x[(size_t)i * 5 + 2], vy = x[(size_t)i * 5 + 3];
        float ty = x[(size_t)i * 5 + 4];
        float mask = (ty == 1.0f) ? 1.0f : 0.0f;
        float nvx = fminf(fmaxf(vx + u0 * ACCEL_SCALE * mask, -MAX_VEL), MAX_VEL);
        float nvy = fminf(fmaxf(vy + u1 * ACCEL_SCALE * mask, -MAX_VEL), MAX_VEL);
        float npx = px + nvx, npy = py + nvy;

        out[(size_t)i * 5]     = npx;
        out[(size_t)i * 5 + 1] = npy;
        out[(size_t)i * 5 + 2] = nvx;
        out[(size_t)i * 5 + 3] = nvy;
        out[(size_t)i * 5 + 4] = ty;

        part[0] = fabsf(nvx);
        part[1] = fabsf(nvy);
        float bc = 0.f;
        if (fabsf(npx) > 1.0f) bc += logf(fabsf(npx) + 1e-6f);
        if (fabsf(npy) > 1.0f) bc += logf(fabsf(npy) + 1e-6f);
        part[2] = bc;
        part[3] = (ty == 0.0f && (c & 0xffff) >= 3) ? 1.f : 0.f;
        part[4] = (ty == 1.0f && (c >> 16) < 1) ? 1.f : 0.f;
    }

    __shared__ float sm[4][5];
#pragma unroll
    for (int q = 0; q < 5; ++q)
#pragma unroll
        for (int off = 32; off > 0; off >>= 1)
            part[q] += __shfl_down(part[q], off);
    int lane = threadIdx.x & 63, wid = threadIdx.x >> 6;
    if (lane == 0)
#pragma unroll
        for (int q = 0; q < 5; ++q) sm[wid][q] = part[q];
    __syncthreads();
    if (threadIdx.x == 0) {
#pragma unroll
        for (int q = 0; q < 5; ++q)
            unsafeAtomicAdd(scal + q, sm[0][q] + sm[1][q] + sm[2][q] + sm[3][q]);
    }
}

__global__ void k_tail(const float* __restrict__ scal, float* __restrict__ out, int n)
{
    if (threadIdx.x == 0 && blockIdx.x == 0) {
        size_t base = (size_t)n * 5;
        float invn = 1.0f / (float)n;
        out[base + 0] = scal[0] * invn;
        out[base + 1] = scal[1] * invn;
        out[base + 2] = scal[2];
        out[base + 3] = scal[3];
        out[base + 4] = scal[4];
    }
}

// ------------------- fallback (round-1 atomic path) ------------------------
__global__ __launch_bounds__(256) void k_node_pre_fb(
    const float* __restrict__ x, const float* __restrict__ W,
    const float* __restrict__ att_src, const float* __restrict__ att_dst,
    float* __restrict__ npack, int n)
{
    int i = blockIdx.x * 256 + threadIdx.x;
    if (i >= n) return;
    float xr[5];
#pragma unroll
    for (int k = 0; k < 5; ++k) xr[k] = x[(size_t)i * 5 + k];
    float hs[5];
#pragma unroll
    for (int c = 0; c < 5; ++c) {
        float s = 0.f;
#pragma unroll
        for (int k = 0; k < 5; ++k) s += xr[k] * W[k * 5 + c];
        hs[c] = s;
    }
    float a_s = 0.f, a_d = 0.f;
#pragma unroll
    for (int c = 0; c < 5; ++c) { a_s += hs[c] * att_src[c]; a_d += hs[c] * att_dst[c]; }
    *(float4*)(npack + (size_t)i * 8)     = make_float4(hs[0], hs[1], hs[2], hs[3]);
    *(float4*)(npack + (size_t)i * 8 + 4) = make_float4(hs[4], a_s, a_d, 0.f);
}

__global__ __launch_bounds__(256) void k_edge_fb(
    const int* __restrict__ ei, const float* __restrict__ ea,
    const float* __restrict__ We, const float* __restrict__ att_edge,
    const float* __restrict__ npack, float* __restrict__ acc,
    int* __restrict__ cnt, int nE)
{
    int e = blockIdx.x * 256 + threadIdx.x;
    if (e >= nE) return;
    float v0 = 0.f, v1 = 0.f;
#pragma unroll
    for (int c = 0; c < 5; ++c) { v0 += We[c] * att_edge[c]; v1 += We[5 + c] * att_edge[c]; }
    int s = ei[e];
    int d = ei[nE + e];
    float2 at = *(const float2*)(ea + (size_t)e * 2);
    const float4 p0 = *(const float4*)(npack + (size_t)s * 8);
    const float2 p1 = *(const float2*)(npack + (size_t)s * 8 + 4);
    float a_dst_d = npack[(size_t)d * 8 + 6];
    float z = p1.y + a_dst_d + (at.x * v0 + at.y * v1);
    float l = z > 0.f ? z : NEG_SLOPE * z;
    float ev = __expf(l);
    float* ad = acc + (size_t)d * 8;
    unsafeAtomicAdd(ad + 0, ev * p0.x);
    unsafeAtomicAdd(ad + 1, ev * p0.y);
    unsafeAtomicAdd(ad + 2, ev * p0.z);
    unsafeAtomicAdd(ad + 3, ev * p0.w);
    unsafeAtomicAdd(ad + 4, ev * p1.x);
    unsafeAtomicAdd(ad + 5, ev);
    int cb = (at.x < CONSUME_R ? 1 : 0) | (at.y == 1.0f ? (1 << 16) : 0);
    if (cb) atomicAdd(cnt + s, cb);
}

__global__ __launch_bounds__(256) void k_final_fb(
    const float* __restrict__ x, const float* __restrict__ acc,
    const int* __restrict__ cnt,
    const float* __restrict__ gat_bias, const float* __restrict__ W1,
    const float* __restrict__ b1, const float* __restrict__ W2,
    const float* __restrict__ b2,
    float* __restrict__ out, float* __restrict__ scal, int n)
{
    int i = blockIdx.x * 256 + threadIdx.x;
    float part[5] = {0.f, 0.f, 0.f, 0.f, 0.f};
    if (i < n) {
        const float* a = acc + (size_t)i * 8;
        float inv = 1.0f / fmaxf(a[5], 1e-16f);
        float h[5];
#pragma unroll
        for (int c = 0; c < 5; ++c) h[c] = a[c] * inv + gat_bias[c];
        float tt[5];
#pragma unroll
        for (int c = 0; c < 5; ++c) {
            float s = b1[c];
#pragma unroll
            for (int k = 0; k < 5; ++k) s += h[k] * W1[k * 5 + c];
            tt[c] = fmaxf(s, 0.f);
        }
        float u0 = b2[0], u1 = b2[1];
#pragma unroll
        for (int k = 0; k < 5; ++k) { u0 += tt[k] * W2[k * 2]; u1 += tt[k] * W2[k * 2 + 1]; }
        u0 = fmaxf(u0, 0.f) * 2.f - 1.f;
        u1 = fmaxf(u1, 0.f) * 2.f - 1.f;
        float px = x[(size_t)i * 5],     py = x[(size_t)i * 5 + 1];
        float vx = x[(size_t)i * 5 + 2], vy = x[(size_t)i * 5 + 3];
        float ty = x[(size_t)i * 5 + 4];
        float mask = (ty == 1.0f) ? 1.0f : 0.0f;
        float nvx = fminf(fmaxf(vx + u0 * ACCEL_SCALE * mask, -MAX_VEL), MAX_VEL);
        float nvy = fminf(fmaxf(vy + u1 * ACCEL_SCALE * mask, -MAX_VEL), MAX_VEL);
        float npx = px + nvx, npy = py + nvy;
        out[(size_t)i * 5]     = npx;
        out[(size_t)i * 5 + 1] = npy;
        out[(size_t)i * 5 + 2] = nvx;
        out[(size_t)i * 5 + 3] = nvy;
        out[(size_t)i * 5 + 4] = ty;
        part[0] = fabsf(nvx);
        part[1] = fabsf(nvy);
        float bc = 0.f;
        if (fabsf(npx) > 1.0f) bc += logf(fabsf(npx) + 1e-6f);
        if (fabsf(npy) > 1.0f) bc += logf(fabsf(npy) + 1e-6f);
        part[2] = bc;
        int c = cnt[i];
        part[3] = (ty == 0.0f && (c & 0xffff) >= 3) ? 1.f : 0.f;
        part[4] = (ty == 1.0f && (c >> 16) < 1) ? 1.f : 0.f;
    }
    __shared__ float sm[4][5];
#pragma unroll
    for (int q = 0; q < 5; ++q)
#pragma unroll
        for (int off = 32; off > 0; off >>= 1)
            part[q] += __shfl_down(part[q], off);
    int lane = threadIdx.x & 63, wid = threadIdx.x >> 6;
    if (lane == 0)
#pragma unroll
        for (int q = 0; q < 5; ++q) sm[wid][q] = part[q];
    __syncthreads();
    if (threadIdx.x == 0) {
#pragma unroll
        for (int q = 0; q < 5; ++q)
            unsafeAtomicAdd(scal + q, sm[0][q] + sm[1][q] + sm[2][q] + sm[3][q]);
    }
}

// ---------------------------------------------------------------------------
extern "C" void kernel_launch(void* const* d_in, const int* in_sizes, int n_in,
                              void* d_out, int out_size, void* d_ws, size_t ws_size,
                              hipStream_t stream)
{
    const float* x        = (const float*)d_in[0];
    const int*   ei       = (const int*)  d_in[1];
    const float* ea       = (const float*)d_in[2];
    const float* W        = (const float*)d_in[3];
    const float* att_src  = (const float*)d_in[4];
    const float* att_dst  = (const float*)d_in[5];
    const float* We       = (const float*)d_in[6];
    const float* att_edge = (const float*)d_in[7];
    const float* gat_bias = (const float*)d_in[8];
    const float* W1       = (const float*)d_in[9];
    const float* b1       = (const float*)d_in[10];
    const float* W2       = (const float*)d_in[11];
    const float* b2       = (const float*)d_in[12];

    int n  = in_sizes[0] / 5;
    int nE = in_sizes[1] / 2;

    unsigned npb = (unsigned)((n + NBUCK - 1) / NBUCK);
    int NB = (nE + EPB - 1) / EPB;
    int G = (NB + MAXSPG - 1) / MAXSPG;
    int SPG = (NB + G - 1) / G;

    size_t o = 0;
    auto alloc = [&](size_t bytes) { size_t r = o; o = (o + bytes + 63) & ~63ULL; return r; };
    size_t off_aS    = alloc((size_t)n * 4);
    size_t off_aD    = alloc((size_t)n * 4);
    size_t off_hpack = alloc((size_t)n * 16);
    size_t off_scal  = alloc(64);
    size_t off_dirD  = alloc((size_t)(NBUCK + 1) * NB * 4);
    size_t off_dirS  = alloc((size_t)(NBUCK + 1) * NB * 4);
    size_t off_accp  = alloc((size_t)G * n * 24);
    size_t off_cntp  = alloc((size_t)G * n * 4);
    size_t off_payD  = alloc((size_t)NB * EPB * 8);
    size_t off_payS  = alloc((size_t)NB * EPB * 2);
    size_t need = o;

    char* wsb = (char*)d_ws;
    bool fast = (ws_size >= need) && (n < (1 << 18)) && (npb <= MAXNPB) && (SPG <= MAXSPG);

    if (fast) {
        float*          aS    = (float*)(wsb + off_aS);
        float*          aD    = (float*)(wsb + off_aD);
        uint4*          hpack = (uint4*)(wsb + off_hpack);
        float*          scal  = (float*)(wsb + off_scal);
        int*            dirD  = (int*)(wsb + off_dirD);
        int*            dirS  = (int*)(wsb + off_dirS);
        float*          accp  = (float*)(wsb + off_accp);
        int*            cntp  = (int*)(wsb + off_cntp);
        int2*           payD  = (int2*)(wsb + off_payD);
        unsigned short* payS  = (unsigned short*)(wsb + off_payS);
        float inv_npb = 1.0f / (float)npb;

        hipMemsetAsync(scal, 0, 64, stream);
        k_pre<<<(n + 255) / 256, 256, 0, stream>>>(x, W, att_src, att_dst, aS, aD, hpack, n);
        k_scatter1<<<NB, TPB, 0, stream>>>(ei, ea, aS, We, att_edge,
                                           payD, payS, dirD, dirS, NB, nE, npb, inv_npb);
        k_accum<<<NBUCK * G, 1024, 0, stream>>>(payD, payS, dirD, dirS, hpack, aD,
                                                accp, cntp, NB, G, SPG, n, npb);
        k_final<<<(n + 255) / 256, 256, 0, stream>>>(x, accp, cntp, G, gat_bias, W1, b1,
                                                     W2, b2, (float*)d_out, scal, n);
        k_tail<<<1, 64, 0, stream>>>(scal, (float*)d_out, n);
    } else {
        float* ws    = (float*)d_ws;
        float* npack = ws;
        float* acc   = ws + (size_t)n * 8;
        int*   cnt   = (int*)(acc + (size_t)n * 8);
        float* scal  = (float*)(cnt + n);
        size_t zbytes = ((size_t)n * 8 + (size_t)n + 8) * sizeof(float);
        hipMemsetAsync(acc, 0, zbytes, stream);
        k_node_pre_fb<<<(n + 255) / 256, 256, 0, stream>>>(x, W, att_src, att_dst, npack, n);
        k_edge_fb<<<(nE + 255) / 256, 256, 0, stream>>>(ei, ea, We, att_edge, npack,
                                                        acc, cnt, nE);
        k_final_fb<<<(n + 255) / 256, 256, 0, stream>>>(x, acc, cnt, gat_bias, W1, b1,
                                                        W2, b2, (float*)d_out, scal, n);
        k_tail<<<1, 64, 0, stream>>>(scal, (float*)d_out, n);
    }
}